// Round 8
// baseline (63.699 us; speedup 1.0000x reference)
//
#include <hip/hip_runtime.h>

#define NPART 2048
#define KMAX 256
#define CUT2 0.09f
#define NW 4                        // waves per center (1 block = 1 center)
#define SEG (NPART / NW)            // 512 particles per wave segment
#define RPW (SEG / 64)              // 8 rounds per wave

__global__ __launch_bounds__(256) void nbr_kernel(
    const float* __restrict__ pos,
    int* __restrict__ out_neigh,
    int* __restrict__ out_cell,
    int* __restrict__ blk_total)    // d_ws: per-block totals, NO atomics
{
#pragma clang fp contract(off)
    __shared__ int cnt[27][NW];            // per-(cell,wave) hit counts
    __shared__ unsigned short myl[KMAX];   // hit list: j = s*2048+p (<55296)

    const int t    = threadIdx.x;
    const int wave = t >> 6;
    const int lane = t & 63;
    const int i    = blockIdx.x;           // this block's center
    const int pb   = wave * SEG;           // wave's particle segment base

    // register-resident segment: 24 batched loads, one vmcnt wait at use
    float px[RPW], py[RPW], pz[RPW];
#pragma unroll
    for (int u = 0; u < RPW; ++u) {
        const int p = pb + (u << 6) + lane;
        px[u] = pos[3 * p + 0];
        py[u] = pos[3 * p + 1];
        pz[u] = pos[3 * p + 2];
    }
    const float cx = pos[3 * i + 0];       // broadcast via cache
    const float cy = pos[3 * i + 1];
    const float cz = pos[3 * i + 2];

    // wave-uniform cell prune: min distance from center to shifted unit box
    unsigned int amask = 0;
#pragma clang loop unroll(disable)
    for (int s = 0; s < 27; ++s) {
        const int s3 = s / 3, s9 = s / 9;
        const float fx = (float)(s - 3 * s3 - 1);
        const float fy = (float)(s3 - 3 * s9 - 1);
        const float fz = (float)(s9 - 1);
        const float dx = fmaxf(fmaxf(fx - cx, cx - (fx + 1.0f)), 0.0f);
        const float dy = fmaxf(fmaxf(fy - cy, cy - (fy + 1.0f)), 0.0f);
        const float dz = fmaxf(fmaxf(fz - cz, cz - (fz + 1.0f)), 0.0f);
        const float dmin2 = dx * dx + dy * dy + dz * dz;
        if (dmin2 <= 0.0901f) amask |= (1u << s);   // margin >> f32 rounding
    }
    amask = __builtin_amdgcn_readfirstlane(amask);  // identical across block

    int total = 0;                         // running center-wide hit count

    // hot loop: ONE code copy (s-loop not unrolled) -> L1I-resident
#pragma clang loop unroll(disable)
    for (int s = 0; s < 27; ++s) {
        if (!((amask >> s) & 1u)) continue;          // block-uniform skip
        const int s3 = s / 3, s9 = s / 9;
        const int cxi = s - 3 * s3 - 1;
        const int cyi = s3 - 3 * s9 - 1;
        const int czi = s9 - 1;
        const float fx = (float)cxi, fy = (float)cyi, fz = (float)czi;
        const bool selfcell = (s == 13);

        // eval: 8 register rounds, save ballots
        unsigned long long m[RPW];
        int mycnt = 0;
#pragma unroll
        for (int u = 0; u < RPW; ++u) {
            const int p = pb + (u << 6) + lane;
            // exact reference op order: n = shift + p ; d = n - c ; no fma
            const float nx = fx + px[u];
            const float ny = fy + py[u];
            const float nz = fz + pz[u];
            const float dx = nx - cx;
            const float dy = ny - cy;
            const float dz = nz - cz;
            const float d2 = (dx * dx + dy * dy) + dz * dz;
            bool hit = (d2 <= CUT2);
            if (selfcell && p == i) hit = false;
            m[u] = __ballot(hit);
            mycnt += (int)__popcll(m[u]);
        }

        // merge: publish per-wave count, single barrier, compute bases
        if (lane == 0) cnt[s][wave] = mycnt;
        __syncthreads();
        const int c0 = cnt[s][0], c1 = cnt[s][1];
        const int c2 = cnt[s][2], c3 = cnt[s][3];
        int base = total;
        if (wave > 0) base += c0;
        if (wave > 1) base += c1;
        if (wave > 2) base += c2;
        total += c0 + c1 + c2 + c3;

        // write hits in exact j order: segment asc -> round asc -> lane rank
#pragma unroll
        for (int u = 0; u < RPW; ++u) {
            const unsigned long long mu = m[u];
            if ((mu >> lane) & 1ull) {
                const int rank = __popcll(mu & ((1ull << lane) - 1ull));
                const int slot = base + rank;
                if (slot < KMAX)
                    myl[slot] = (unsigned short)((s << 11) + pb + (u << 6) + lane);
            }
            base += (int)__popcll(mu);
        }
    }
    __syncthreads();

    // flush: 256 threads, one slot each; tail fill fused
    // tail: neighbours = -1, cell = shifts[26] = (1,1,1)  (jnp.take wrap)
    const int obase = i * KMAX;
    {
        int nv, cxo, cyo, czo;
        if (t < total) {
            const int j = (int)myl[t];
            const int s = j >> 11;
            const int s3 = s / 3, s9 = s / 9;
            nv  = j & 2047;
            cxo = s - 3 * s3 - 1;
            cyo = s3 - 3 * s9 - 1;
            czo = s9 - 1;
        } else {
            nv = -1; cxo = 1; cyo = 1; czo = 1;
        }
        out_neigh[obase + t] = nv;
        const int cb = (obase + t) * 3;
        out_cell[cb + 0] = cxo;
        out_cell[cb + 1] = cyo;
        out_cell[cb + 2] = czo;
    }

    // per-block total -> distinct address; NO same-address atomic storm
    if (t == 0) blk_total[i] = total;
}

// tiny second dispatch: max-reduce 2048 per-block totals -> out_max
__global__ __launch_bounds__(256) void max_kernel(
    const int* __restrict__ blk_total,
    int* __restrict__ out_max)
{
    __shared__ int wmax[4];
    const int t    = threadIdx.x;
    const int wave = t >> 6;
    const int lane = t & 63;

    int v = blk_total[t];
#pragma unroll
    for (int k = 1; k < NPART / 256; ++k)
        v = max(v, blk_total[k * 256 + t]);
#pragma unroll
    for (int d = 32; d > 0; d >>= 1)
        v = max(v, __shfl_xor(v, d, 64));
    if (lane == 0) wmax[wave] = v;
    __syncthreads();
    if (t == 0)
        *out_max = max(max(wmax[0], wmax[1]), max(wmax[2], wmax[3]));
}

extern "C" void kernel_launch(void* const* d_in, const int* in_sizes, int n_in,
                              void* d_out, int out_size, void* d_ws, size_t ws_size,
                              hipStream_t stream)
{
    const float* pos = (const float*)d_in[0];   // (2048,3) f32
    int* out       = (int*)d_out;
    int* out_neigh = out;                        // (2048,256)
    int* out_cell  = out + NPART * KMAX;         // (2048,256,3)
    int* out_max   = out + NPART * KMAX * 4;     // scalar
    int* blk_total = (int*)d_ws;                 // 2048 ints scratch

    // SLOPE DIAGNOSTIC (R7): launch the main kernel TWICE. Idempotent —
    // every output word is rewritten with identical deterministic values.
    // dur_us(R7) - dur_us(R6) = true nbr_kernel duration, independent of
    // the fillBuffer ops masking rocprof's top-5 table.
    nbr_kernel<<<NPART, 256, 0, stream>>>(pos, out_neigh, out_cell, blk_total);
    nbr_kernel<<<NPART, 256, 0, stream>>>(pos, out_neigh, out_cell, blk_total);
    max_kernel<<<1, 256, 0, stream>>>(blk_total, out_max);
}

// Round 9
// 39.389 us; speedup vs baseline: 1.6172x; 1.6172x over previous
//
#include <hip/hip_runtime.h>

#define NPART 2048
#define KMAX 256
#define CUT2 0.09f
#define NW 4                        // waves per block
#define SEG (NPART / NW)            // 512 particles per wave segment
#define RPW (SEG / 64)              // 8 rounds per wave
#define CPB 2                       // centers per block (persistent-2)
#define NBLK (NPART / CPB)          // 1024 blocks

__global__ __launch_bounds__(256) void nbr_kernel(
    const float* __restrict__ pos,
    int* __restrict__ out_neigh,
    int* __restrict__ out_cell,
    int* __restrict__ blk_total)    // d_ws: per-center totals, NO atomics
{
#pragma clang fp contract(off)
    __shared__ int cnt[27][NW];            // per-(cell,wave) hit counts
    __shared__ unsigned short myl[KMAX];   // hit list: j = s*2048+p (<55296)

    const int t    = threadIdx.x;
    const int wave = t >> 6;
    const int lane = t & 63;
    const int pb   = wave * SEG;           // wave's particle segment base

    // register-resident segment: staged ONCE, reused for both centers
    float px[RPW], py[RPW], pz[RPW];
#pragma unroll
    for (int u = 0; u < RPW; ++u) {
        const int p = pb + (u << 6) + lane;
        px[u] = pos[3 * p + 0];
        py[u] = pos[3 * p + 1];
        pz[u] = pos[3 * p + 2];
    }

    for (int c = 0; c < CPB; ++c) {
        const int i = blockIdx.x * CPB + c;    // this center
        __syncthreads();                       // myl/cnt reuse hazard between centers

        const float cx = pos[3 * i + 0];       // broadcast via cache
        const float cy = pos[3 * i + 1];
        const float cz = pos[3 * i + 2];

        // wave-uniform cell prune: min distance from center to shifted unit box
        unsigned int amask = 0;
        for (int s = 0; s < 27; ++s) {
            const int s3 = s / 3, s9 = s / 9;
            const float fx = (float)(s - 3 * s3 - 1);
            const float fy = (float)(s3 - 3 * s9 - 1);
            const float fz = (float)(s9 - 1);
            const float dx = fmaxf(fmaxf(fx - cx, cx - (fx + 1.0f)), 0.0f);
            const float dy = fmaxf(fmaxf(fy - cy, cy - (fy + 1.0f)), 0.0f);
            const float dz = fmaxf(fmaxf(fz - cz, cz - (fz + 1.0f)), 0.0f);
            const float dmin2 = dx * dx + dy * dy + dz * dz;
            if (dmin2 <= 0.0901f) amask |= (1u << s);   // margin >> f32 rounding
        }
        amask = __builtin_amdgcn_readfirstlane(amask);  // identical across block

        int total = 0;                         // running center-wide hit count

        // hot loop: ONE code copy (s-loop not unrolled) -> L1I-resident
#pragma clang loop unroll(disable)
        for (int s = 0; s < 27; ++s) {
            if (!((amask >> s) & 1u)) continue;          // block-uniform skip
            const int s3 = s / 3, s9 = s / 9;
            const float fx = (float)(s - 3 * s3 - 1);
            const float fy = (float)(s3 - 3 * s9 - 1);
            const float fz = (float)(s9 - 1);
            const bool selfcell = (s == 13);

            // eval: 8 register rounds, save ballots
            unsigned long long m[RPW];
            int mycnt = 0;
#pragma unroll
            for (int u = 0; u < RPW; ++u) {
                const int p = pb + (u << 6) + lane;
                // exact reference op order: n = shift + p ; d = n - c ; no fma
                const float nx = fx + px[u];
                const float ny = fy + py[u];
                const float nz = fz + pz[u];
                const float dx = nx - cx;
                const float dy = ny - cy;
                const float dz = nz - cz;
                const float d2 = (dx * dx + dy * dy) + dz * dz;
                bool hit = (d2 <= CUT2);
                if (selfcell && p == i) hit = false;
                m[u] = __ballot(hit);
                mycnt += (int)__popcll(m[u]);
            }

            // merge: publish per-wave count, single barrier, compute bases
            if (lane == 0) cnt[s][wave] = mycnt;
            __syncthreads();
            const int c0 = cnt[s][0], c1 = cnt[s][1];
            const int c2 = cnt[s][2], c3 = cnt[s][3];
            int base = total;
            if (wave > 0) base += c0;
            if (wave > 1) base += c1;
            if (wave > 2) base += c2;
            total += c0 + c1 + c2 + c3;

            // write hits in exact j order: segment asc -> round asc -> lane rank
#pragma unroll
            for (int u = 0; u < RPW; ++u) {
                const unsigned long long mu = m[u];
                if ((mu >> lane) & 1ull) {
                    const int rank = __popcll(mu & ((1ull << lane) - 1ull));
                    const int slot = base + rank;
                    if (slot < KMAX)
                        myl[slot] = (unsigned short)((s << 11) + pb + (u << 6) + lane);
                }
                base += (int)__popcll(mu);
            }
        }
        __syncthreads();

        // flush: 256 threads, one slot each; tail fill fused
        // tail: neighbours = -1, cell = shifts[26] = (1,1,1)  (jnp.take wrap)
        const int obase = i * KMAX;
        {
            int nv, cxo, cyo, czo;
            if (t < total) {
                const int j = (int)myl[t];
                const int s = j >> 11;
                const int s3 = s / 3, s9 = s / 9;
                nv  = j & 2047;
                cxo = s - 3 * s3 - 1;
                cyo = s3 - 3 * s9 - 1;
                czo = s9 - 1;
            } else {
                nv = -1; cxo = 1; cyo = 1; czo = 1;
            }
            out_neigh[obase + t] = nv;
            const int cb = (obase + t) * 3;
            out_cell[cb + 0] = cxo;
            out_cell[cb + 1] = cyo;
            out_cell[cb + 2] = czo;
        }

        // per-center total -> distinct address; no same-address atomics
        if (t == 0) blk_total[i] = total;
    }
}

// tiny second dispatch: max-reduce 2048 per-center totals -> out_max
__global__ __launch_bounds__(256) void max_kernel(
    const int* __restrict__ blk_total,
    int* __restrict__ out_max)
{
    __shared__ int wmax[4];
    const int t    = threadIdx.x;
    const int wave = t >> 6;
    const int lane = t & 63;

    int v = blk_total[t];
#pragma unroll
    for (int k = 1; k < NPART / 256; ++k)
        v = max(v, blk_total[k * 256 + t]);
#pragma unroll
    for (int d = 32; d > 0; d >>= 1)
        v = max(v, __shfl_xor(v, d, 64));
    if (lane == 0) wmax[wave] = v;
    __syncthreads();
    if (t == 0)
        *out_max = max(max(wmax[0], wmax[1]), max(wmax[2], wmax[3]));
}

extern "C" void kernel_launch(void* const* d_in, const int* in_sizes, int n_in,
                              void* d_out, int out_size, void* d_ws, size_t ws_size,
                              hipStream_t stream)
{
    const float* pos = (const float*)d_in[0];   // (2048,3) f32
    int* out       = (int*)d_out;
    int* out_neigh = out;                        // (2048,256)
    int* out_cell  = out + NPART * KMAX;         // (2048,256,3)
    int* out_max   = out + NPART * KMAX * 4;     // scalar
    int* blk_total = (int*)d_ws;                 // 2048 ints scratch

    nbr_kernel<<<NBLK, 256, 0, stream>>>(pos, out_neigh, out_cell, blk_total);
    max_kernel<<<1, 256, 0, stream>>>(blk_total, out_max);
}

// Round 10
// 17.234 us; speedup vs baseline: 3.6962x; 2.2856x over previous
//
#include <hip/hip_runtime.h>

#define NPART 2048
#define KMAX 256
#define CUT2 0.09f
#define NW 4                         // waves (centers) per block
#define NBLK (NPART / NW)            // 512 blocks
#define CAP 448                      // raw hit-list capacity (expected ~231, max ~290)
#define NCH 4                        // chunks
#define RPC 8                        // rounds per chunk (NCH*RPC*64 = 2048)

__global__ __launch_bounds__(256) void nbr_kernel(
    const float* __restrict__ pos,
    int* __restrict__ out_neigh,
    int* __restrict__ out_cell,
    int* __restrict__ blk_total)     // d_ws: per-center totals, NO atomics
{
#pragma clang fp contract(off)
    __shared__ __attribute__((aligned(16))) float sp[NPART * 3];  // 24 KB linear xyz
    __shared__ unsigned short raw[NW][CAP];   // p-ordered hits, j16 = (s<<11)|p
    __shared__ unsigned short srt[NW][KMAX];  // j-sorted first 256
    __shared__ int hist[NW][27];
    __shared__ int cursor[NW][27];

    const int t    = threadIdx.x;
    const int wave = t >> 6;
    const int lane = t & 63;
    const int i    = blockIdx.x * NW + wave;          // this wave's center
    const unsigned long long lowmask = (1ull << lane) - 1ull;

    // staging: 1536 coalesced float4 loads -> linear LDS copy
    const float4* __restrict__ pos4 = (const float4*)pos;
    float4* sp4 = (float4*)sp;
#pragma unroll
    for (int k = 0; k < 6; ++k)
        sp4[t + 256 * k] = pos4[t + 256 * k];
    if (lane < 27) hist[wave][lane] = 0;              // own wave's bins
    __syncthreads();

    const float cx = sp[3 * i + 0];                   // uniform LDS broadcast
    const float cy = sp[3 * i + 1];
    const float cz = sp[3 * i + 2];

    int total = 0;                                    // uncapped hit count

    // ===== pass 1: nearest-image eval, ONE cell per pair, no barriers =====
    for (int ch = 0; ch < NCH; ++ch) {
        float ax[RPC], ay[RPC], az[RPC];
#pragma unroll
        for (int u = 0; u < RPC; ++u) {               // batched LDS reads
            const int p = ((ch * RPC + u) << 6) + lane;
            ax[u] = sp[3 * p + 0];
            ay[u] = sp[3 * p + 1];
            az[u] = sp[3 * p + 2];
        }
#pragma unroll
        for (int u = 0; u < RPC; ++u) {
            const int p = ((ch * RPC + u) << 6) + lane;
            // selection: nearest image g = rint(p - c)  (= -shift)
            const float rx = ax[u] - cx;
            const float ry = ay[u] - cy;
            const float rz = az[u] - cz;
            const float gx = __builtin_rintf(rx);
            const float gy = __builtin_rintf(ry);
            const float gz = __builtin_rintf(rz);
            // exact reference arithmetic: nx = fx + px (== px - gx); dx = nx - cx
            const float nx = ax[u] - gx;
            const float ny = ay[u] - gy;
            const float nz = az[u] - gz;
            const float dx = nx - cx;
            const float dy = ny - cy;
            const float dz = nz - cz;
            const float d2 = (dx * dx + dy * dy) + dz * dz;
            // non-selected cells have |dx'| >= 0.5-3ulp > 0.3 -> can never hit.
            // self (p==i) falls in s=13 exactly -> p!=i reproduces include_self=False.
            const bool hit = (d2 <= CUT2) && (p != i);
            const unsigned long long m = __ballot(hit);
            if (hit) {
                const float sf = ((13.0f - gx) - 3.0f * gy) - 9.0f * gz;  // exact small ints
                const int s = (int)sf;
                const int rank = (int)__popcll(m & lowmask);
                const int slot = total + rank;
                if (slot < CAP)
                    raw[wave][slot] = (unsigned short)((s << 11) + p);
            }
            total += (int)__popcll(m);
        }
    }

    const int nlist = min(total, CAP);

    // ===== pass 2: histogram of s (match-any via 5 ballots) =====
    for (int k0 = 0; k0 < nlist; k0 += 64) {
        const int k = k0 + lane;
        const bool v = (k < nlist);
        const int s = v ? (raw[wave][k] >> 11) : 31;
        unsigned long long mm = ~0ull;
#pragma unroll
        for (int b = 0; b < 5; ++b) {
            const unsigned long long bb = __ballot((s >> b) & 1);
            mm &= ((s >> b) & 1) ? bb : ~bb;
        }
        if (v && (mm & lowmask) == 0)                 // group leader (lowest lane)
            atomicAdd(&hist[wave][s], (int)__popcll(mm));
    }

    // ===== scan: exclusive prefix over 27 bins -> cursor bases =====
    {
        const int c = (lane < 27) ? hist[wave][lane] : 0;
        int x = c;
#pragma unroll
        for (int d = 1; d < 32; d <<= 1) {
            const int o = __shfl_up(x, d, 64);
            if (lane >= d) x += o;
        }
        if (lane < 27) cursor[wave][lane] = x - c;    // exclusive base
    }

    // ===== pass 3: stable counting-sort scatter (p-order preserved per bin) =====
    for (int k0 = 0; k0 < nlist; k0 += 64) {
        const int k = k0 + lane;
        const bool v = (k < nlist);
        const unsigned short j = v ? raw[wave][k] : 0;
        const int s = v ? (j >> 11) : 31;
        unsigned long long mm = ~0ull;
#pragma unroll
        for (int b = 0; b < 5; ++b) {
            const unsigned long long bb = __ballot((s >> b) & 1);
            mm &= ((s >> b) & 1) ? bb : ~bb;
        }
        int bs = 0;
        if (v) bs = cursor[wave][s];                  // all reads precede writes
        if (v) {
            const int rank = (int)__popcll(mm & lowmask);
            const int slot = bs + rank;
            if (slot < KMAX) srt[wave][slot] = j;
        }
        if (v && (mm & ~((2ull << lane) - 1ull)) == 0)   // highest lane of group
            cursor[wave][s] = bs + (int)__popcll(mm);
    }

    // ===== flush: coalesced output + fused tail =====
    // tail: neighbours = -1, cell = shifts[26] = (1,1,1)  (jnp.take wrap)
    const int obase = i * KMAX;
    const int nout = min(total, KMAX);
#pragma unroll
    for (int r = 0; r < 4; ++r) {
        const int k = (r << 6) + lane;
        int nv, cxo, cyo, czo;
        if (k < nout) {
            const int j = (int)srt[wave][k];
            const int s = j >> 11;
            const int s3 = s / 3, s9 = s / 9;
            nv  = j & 2047;
            cxo = s - 3 * s3 - 1;
            cyo = s3 - 3 * s9 - 1;
            czo = s9 - 1;
        } else {
            nv = -1; cxo = 1; cyo = 1; czo = 1;
        }
        out_neigh[obase + k] = nv;
        const int cb = (obase + k) * 3;
        out_cell[cb + 0] = cxo;
        out_cell[cb + 1] = cyo;
        out_cell[cb + 2] = czo;
    }

    if (lane == 0) blk_total[i] = total;              // uncapped, distinct addr
}

// tiny second dispatch: max-reduce 2048 per-center totals -> out_max
__global__ __launch_bounds__(256) void max_kernel(
    const int* __restrict__ blk_total,
    int* __restrict__ out_max)
{
    __shared__ int wmax[4];
    const int t    = threadIdx.x;
    const int wave = t >> 6;
    const int lane = t & 63;

    int v = blk_total[t];
#pragma unroll
    for (int k = 1; k < NPART / 256; ++k)
        v = max(v, blk_total[k * 256 + t]);
#pragma unroll
    for (int d = 32; d > 0; d >>= 1)
        v = max(v, __shfl_xor(v, d, 64));
    if (lane == 0) wmax[wave] = v;
    __syncthreads();
    if (t == 0)
        *out_max = max(max(wmax[0], wmax[1]), max(wmax[2], wmax[3]));
}

extern "C" void kernel_launch(void* const* d_in, const int* in_sizes, int n_in,
                              void* d_out, int out_size, void* d_ws, size_t ws_size,
                              hipStream_t stream)
{
    const float* pos = (const float*)d_in[0];   // (2048,3) f32
    int* out       = (int*)d_out;
    int* out_neigh = out;                        // (2048,256)
    int* out_cell  = out + NPART * KMAX;         // (2048,256,3)
    int* out_max   = out + NPART * KMAX * 4;     // scalar
    int* blk_total = (int*)d_ws;                 // 2048 ints scratch

    nbr_kernel<<<NBLK, 256, 0, stream>>>(pos, out_neigh, out_cell, blk_total);
    max_kernel<<<1, 256, 0, stream>>>(blk_total, out_max);
}

// Round 11
// 14.899 us; speedup vs baseline: 4.2754x; 1.1567x over previous
//
#include <hip/hip_runtime.h>

#define NPART 2048
#define KMAX 256
#define CUT2 0.09f
#define CPB 2                        // centers per block
#define NBLK (NPART / CPB)           // 1024 blocks
#define HALF 1024                    // particles per half-wave
#define CAP 448                      // raw hit-list capacity per half (R9-safe)
#define NCH 2                        // chunks per wave
#define RPC 8                        // rounds per chunk (2*8*64 = 1024)

__global__ __launch_bounds__(256) void nbr_kernel(
    const float* __restrict__ pos,
    int* __restrict__ out_neigh,
    int* __restrict__ out_cell,
    int* __restrict__ out_max)
{
#pragma clang fp contract(off)
    __shared__ __attribute__((aligned(16))) float sp[NPART * 3];  // 24 KB linear xyz
    __shared__ unsigned short raw[4][CAP];    // per-wave p-ordered hits, (s<<11)|p
    __shared__ unsigned short srt[CPB][KMAX]; // per-center j-sorted first 256
    __shared__ int hist[4][27];               // per-wave s-histogram
    __shared__ int cursor[4][27];             // per-wave scatter cursors
    __shared__ int wtot[4];                   // per-wave uncapped totals

    const int t    = threadIdx.x;
    const int wave = t >> 6;
    const int lane = t & 63;
    const int c    = wave >> 1;               // center slot in block (0..1)
    const int half = wave & 1;                // particle half (0: p<1024)
    const int i    = blockIdx.x * CPB + c;    // this wave's center
    const int pb   = half * HALF;             // particle base
    const unsigned long long lowmask = (1ull << lane) - 1ull;

    // staging: 1536 coalesced float4 loads -> linear LDS copy
    const float4* __restrict__ pos4 = (const float4*)pos;
    float4* sp4 = (float4*)sp;
#pragma unroll
    for (int k = 0; k < 6; ++k)
        sp4[t + 256 * k] = pos4[t + 256 * k];
    if (lane < 27) hist[wave][lane] = 0;      // own wave's bins
    __syncthreads();

    const float cx = sp[3 * i + 0];           // uniform LDS broadcast
    const float cy = sp[3 * i + 1];
    const float cz = sp[3 * i + 2];

    int total = 0;                            // this wave's uncapped hit count

    // ===== pass 1: nearest-image eval, ONE cell per pair, no barriers =====
    for (int ch = 0; ch < NCH; ++ch) {
        float ax[RPC], ay[RPC], az[RPC];
#pragma unroll
        for (int u = 0; u < RPC; ++u) {       // batched LDS reads
            const int p = pb + ((ch * RPC + u) << 6) + lane;
            ax[u] = sp[3 * p + 0];
            ay[u] = sp[3 * p + 1];
            az[u] = sp[3 * p + 2];
        }
#pragma unroll
        for (int u = 0; u < RPC; ++u) {
            const int p = pb + ((ch * RPC + u) << 6) + lane;
            // selection: nearest image g = rint(p - c)  (= -shift)
            const float rx = ax[u] - cx;
            const float ry = ay[u] - cy;
            const float rz = az[u] - cz;
            const float gx = __builtin_rintf(rx);
            const float gy = __builtin_rintf(ry);
            const float gz = __builtin_rintf(rz);
            // exact reference arithmetic: nx = fx + px (== px - gx); dx = nx - cx
            const float nx = ax[u] - gx;
            const float ny = ay[u] - gy;
            const float nz = az[u] - gz;
            const float dx = nx - cx;
            const float dy = ny - cy;
            const float dz = nz - cz;
            const float d2 = (dx * dx + dy * dy) + dz * dz;
            // non-selected cells: |dx'| >= 0.5-3ulp > 0.3 -> can never hit.
            // self (p==i) lands in s=13 exactly -> p!=i gives include_self=False.
            const bool hit = (d2 <= CUT2) && (p != i);
            const unsigned long long m = __ballot(hit);
            if (hit) {
                const float sf = ((13.0f - gx) - 3.0f * gy) - 9.0f * gz;  // exact ints
                const int s = (int)sf;
                const int rank = (int)__popcll(m & lowmask);
                const int slot = total + rank;
                if (slot < CAP)
                    raw[wave][slot] = (unsigned short)((s << 11) + p);
            }
            total += (int)__popcll(m);
        }
    }
    if (lane == 0) wtot[wave] = total;

    const int nlist = min(total, CAP);

    // ===== pass 2: per-wave histogram of s (match-any via 5 ballots) =====
    for (int k0 = 0; k0 < nlist; k0 += 64) {
        const int k = k0 + lane;
        const bool v = (k < nlist);
        const int s = v ? (raw[wave][k] >> 11) : 31;
        unsigned long long mm = ~0ull;
#pragma unroll
        for (int b = 0; b < 5; ++b) {
            const unsigned long long bb = __ballot((s >> b) & 1);
            mm &= ((s >> b) & 1) ? bb : ~bb;
        }
        if (v && (mm & lowmask) == 0)         // group leader (lowest lane)
            atomicAdd(&hist[wave][s], (int)__popcll(mm));
    }
    __syncthreads();                          // hists + wtot visible block-wide

    // ===== scan: combined per-center histogram -> this wave's bin bases =====
    {
        const int wA = (c << 1), wB = wA + 1;
        const int hA = (lane < 27) ? hist[wA][lane] : 0;
        const int hB = (lane < 27) ? hist[wB][lane] : 0;
        const int cnt = hA + hB;
        int x = cnt;
#pragma unroll
        for (int d = 1; d < 32; d <<= 1) {
            const int o = __shfl_up(x, d, 64);
            if (lane >= d) x += o;
        }
        // bin s: [excl, excl+hA) for half 0, [excl+hA, excl+hA+hB) for half 1
        if (lane < 27) cursor[wave][lane] = (x - cnt) + (half ? hA : 0);
    }

    // ===== pass 3: stable counting-sort scatter (p-order kept per bin) =====
    for (int k0 = 0; k0 < nlist; k0 += 64) {
        const int k = k0 + lane;
        const bool v = (k < nlist);
        const unsigned short j = v ? raw[wave][k] : 0;
        const int s = v ? (j >> 11) : 31;
        unsigned long long mm = ~0ull;
#pragma unroll
        for (int b = 0; b < 5; ++b) {
            const unsigned long long bb = __ballot((s >> b) & 1);
            mm &= ((s >> b) & 1) ? bb : ~bb;
        }
        int bs = 0;
        if (v) bs = cursor[wave][s];          // all reads precede writes
        if (v) {
            const int rank = (int)__popcll(mm & lowmask);
            const int slot = bs + rank;
            if (slot < KMAX) srt[c][slot] = j;
        }
        if (v && (mm & ~((2ull << lane) - 1ull)) == 0)  // highest lane of group
            cursor[wave][s] = bs + (int)__popcll(mm);
    }
    __syncthreads();                          // srt complete for both halves

    // ===== flush: each wave writes its half's 128 output slots =====
    // tail: neighbours = -1, cell = shifts[26] = (1,1,1)  (jnp.take wrap)
    const int ctot = wtot[c << 1] + wtot[(c << 1) + 1];
    const int nout = min(ctot, KMAX);
    const int obase = i * KMAX;
#pragma unroll
    for (int r = 0; r < 2; ++r) {
        const int k = half * 128 + (r << 6) + lane;
        int nv, cxo, cyo, czo;
        if (k < nout) {
            const int j = (int)srt[c][k];
            const int s = j >> 11;
            const int s3 = s / 3, s9 = s / 9;
            nv  = j & 2047;
            cxo = s - 3 * s3 - 1;
            cyo = s3 - 3 * s9 - 1;
            czo = s9 - 1;
        } else {
            nv = -1; cxo = 1; cyo = 1; czo = 1;
        }
        out_neigh[obase + k] = nv;
        const int cb = (obase + k) * 3;
        out_cell[cb + 0] = cxo;
        out_cell[cb + 1] = cyo;
        out_cell[cb + 2] = czo;
    }

    // actual_max: one check-then-atomic per block (atomics proven cheap by
    // R2/R6 A/B; poison 0xAA = negative -> first replay updates; deterministic).
    if (t == 0) {
        const int m = max(wtot[0] + wtot[1], wtot[2] + wtot[3]);
        volatile int* vm = (volatile int*)out_max;
        if (m > *vm) atomicMax(out_max, m);
    }
}

extern "C" void kernel_launch(void* const* d_in, const int* in_sizes, int n_in,
                              void* d_out, int out_size, void* d_ws, size_t ws_size,
                              hipStream_t stream)
{
    const float* pos = (const float*)d_in[0];   // (2048,3) f32
    int* out       = (int*)d_out;
    int* out_neigh = out;                        // (2048,256)
    int* out_cell  = out + NPART * KMAX;         // (2048,256,3)
    int* out_max   = out + NPART * KMAX * 4;     // scalar

    nbr_kernel<<<NBLK, 256, 0, stream>>>(pos, out_neigh, out_cell, out_max);
}